// Round 2
// baseline (761.409 us; speedup 1.0000x reference)
//
#include <hip/hip_runtime.h>
#include <stdint.h>

// MLPAttnGNN round 1: fp32 I/O (round-0 bf16 bet was wrong -> NaN), bf16 MFMA compute.
// Layout bets retained: mfma_f32_16x16x32_bf16 A: row=lane&15, k=(lane>>4)*8+j;
// B: col=lane&15, k=(lane>>4)*8+j; C/D: col=lane&15, row=(lane>>4)*4+reg (m89-verified).

#define NN 20000
#define NE 320000
#define USE_GLOAD 1

typedef unsigned short u16;
typedef __attribute__((ext_vector_type(8))) short bf16x8;
typedef __attribute__((ext_vector_type(4))) float f32x4;

__device__ __forceinline__ float bf2f(u16 u){ union{unsigned i; float f;} v; v.i=((unsigned)u)<<16; return v.f; }
__device__ __forceinline__ u16 f2bf(float f){ union{float f; unsigned i;} v; v.f=f; unsigned r = v.i + 0x7FFFu + ((v.i>>16)&1u); return (u16)(r>>16); }
__device__ __forceinline__ unsigned pk2(float a, float b){ return (unsigned)f2bf(a) | ((unsigned)f2bf(b)<<16); }
__device__ __forceinline__ float gelu_f(float x){ return 0.5f*x*(1.f+erff(x*0.70710678118654752f)); }

typedef __attribute__((address_space(3))) unsigned int as3_uint;
typedef const __attribute__((address_space(1))) unsigned int as1_uint;
__device__ __forceinline__ void gld_lds16(const void* g, void* l){
#if USE_GLOAD
  __builtin_amdgcn_global_load_lds((as1_uint*)(uintptr_t)g,
                                   (as3_uint*)(unsigned int)(uintptr_t)l, 16, 0, 0);
#endif
}

// ---- ws layout ----
// transposed+swizzled bf16 weight images, chunk-major [chunk][Nout][64]
#define WT_E1 0
#define WT_E2 40960
#define WT_W1 49152
#define WT_W2 90112
#define WT_W3 106496
#define WT_V1 108544
#define WT_V2 133120
#define WT_V3 149504
#define WT_O  165888
#define WT_F1 231424
#define WT_F2 247808
#define WT_TOT 264192
// byte offsets in ws
#define AW_B  ((size_t)WT_TOT*2)            // fp32 [E][4] logits
#define AV_B  (AW_B + (size_t)NE*16)        // bf16 [E][128] values
#define AO_B  (AV_B + (size_t)NE*256)       // bf16 [N][512] aggregated
#define CNT_B (AO_B + (size_t)NN*1024)
#define CUR_B (CNT_B + (size_t)NN*4)
#define STA_B (CUR_B + (size_t)NN*4)
#define ORD_B (STA_B + (size_t)(NN+1)*4 + 4)

// ---------------- weight prep: fp32 W[K][N] -> chunk-major swizzled bf16 W image ----------------
struct PrepArgs { const float* src[11]; u16* dst; };

__global__ void prep_kernel(PrepArgs A){
  const int NSrc[11] = {128,64,128,128,4,128,128,128,128,128,128};
  const int NOut[11] = {128,64,128,128,16,128,128,128,128,128,128};
  const int OFF[12]  = {0,40960,49152,90112,106496,108544,133120,149504,165888,231424,247808,264192};
  for (int g = blockIdx.x*blockDim.x + threadIdx.x; g < WT_TOT; g += gridDim.x*blockDim.x){
    int m = 0;
#pragma unroll
    for (int q=0;q<11;q++) if (g >= OFF[q+1]) m = q+1;
    int rel = g - OFF[m];
    int no = NOut[m], ns = NSrc[m];
    int c = rel/(no*64); int r2 = rel - c*no*64; int n = r2>>6; int kk = r2&63;
    int k = c*64 + kk;
    u16 v = (n < ns) ? f2bf(A.src[m][(size_t)k*ns + n]) : (u16)0;
    A.dst[OFF[m] + c*no*64 + ((n*64+kk) ^ ((n&7)<<3))] = v;
  }
}

// ---------------- CSR build ----------------
__global__ void zero_kernel(int* c){ int i = blockIdx.x*256+threadIdx.x; if (i<NN) c[i]=0; }
__global__ void hist_kernel(const int* __restrict__ ei, int* __restrict__ cnt){
  int e = blockIdx.x*256+threadIdx.x; if (e<NE) atomicAdd(&cnt[ei[NE+e]], 1);
}
__global__ void scan_kernel(const int* __restrict__ cnt, int* __restrict__ sta, int* __restrict__ cur){
  __shared__ int part[1024];
  const int t = threadIdx.x;
  const int base = t*20;
  int s = 0;
  for (int i=0;i<20;i++){ int idx=base+i; s += (idx<NN)?cnt[idx]:0; }
  part[t]=s; __syncthreads();
  for (int off=1; off<1024; off<<=1){
    int v = (t>=off)? part[t-off] : 0;
    __syncthreads();
    part[t] += v;
    __syncthreads();
  }
  int run = part[t] - s;
  for (int i=0;i<20;i++){ int idx=base+i; if (idx<NN){ int c=cnt[idx]; sta[idx]=run; cur[idx]=run; run+=c; } }
  if (t==1023) sta[NN] = part[1023];
}
__global__ void place_kernel(const int* __restrict__ ei, int* __restrict__ cur, int* __restrict__ ord){
  int e = blockIdx.x*256+threadIdx.x;
  if (e<NE){ int p = atomicAdd(&cur[ei[NE+e]], 1); ord[p]=e; }
}

// ---------------- generic MFMA stage ----------------
template<int NCH, int NT, int MTT, int NACC>
__device__ __forceinline__ void run_gemm(int tid, int wave, int lane,
    const u16* const (&cb)[NCH], const int (&cs)[NCH], const int (&ck)[NCH],
    const u16* __restrict__ wtG, u16* WT, f32x4 (&acc)[NACC],
    int& ntile, int& mt0, bool& active)
{
  const int lr = lane & 15, lg = lane >> 4;
  active = true;
  if (NT == 8){ ntile = wave; mt0 = 0; }
  else if (NT == 4){ ntile = wave & 3; mt0 = (wave >> 2) * NACC; }
  else { ntile = 0; mt0 = wave; active = (wave < MTT); }
  f32x4 z4 = {0.f,0.f,0.f,0.f};
#pragma unroll
  for (int m=0;m<NACC;m++) acc[m] = z4;
  const int chunkElems = NT*16*64;
#pragma unroll
  for (int c=0;c<NCH;c++){
    __syncthreads();                       // WT consumed / prev stage done
    const u16* src = wtG + c*chunkElems;
#if USE_GLOAD
    for (int s = wave; s < NT*2; s += 8)
      gld_lds16((const char*)src + s*1024 + lane*16, (char*)WT + s*1024);
#else
    for (int v = tid; v < chunkElems/8; v += 512)
      *(uint4*)((char*)WT + v*16) = *(const uint4*)((const char*)src + v*16);
#endif
    __syncthreads();                       // barrier drains vmcnt -> WT ready
    const int n = ntile*16 + lr;
#pragma unroll
    for (int ks=0; ks<2; ks++){
      bf16x8 b = *(const bf16x8*)(WT + ((n*64 + ks*32 + lg*8) ^ ((n&7)<<3)));
      if (active){
#pragma unroll
        for (int m=0;m<NACC;m++){
          const u16* ap = cb[c] + ((mt0+m)*16 + lr)*cs[c] + ck[c] + ks*32 + lg*8;
          bf16x8 a = *(const bf16x8*)ap;
          acc[m] = __builtin_amdgcn_mfma_f32_16x16x32_bf16(a, b, acc[m], 0, 0, 0);
        }
      }
    }
  }
  __syncthreads();
}

template<int NACC>
__device__ __forceinline__ void epi_hb(const f32x4 (&acc)[NACC], int mt0, int ntile, int lg, int lr,
    const float* __restrict__ biasG, u16* dst, int dstride, bool act)
{
  const int col = ntile*16 + lr;
  const float b = biasG[col];
#pragma unroll
  for (int m=0;m<NACC;m++)
#pragma unroll
    for (int j=0;j<4;j++){
      int row = (mt0+m)*16 + lg*4 + j;
      float v = acc[m][j] + b;
      if (act) v = gelu_f(v);
      dst[row*dstride + col] = f2bf(v);
    }
}

// ---------------- edge mega-kernel ----------------
struct EdgeArgs {
  const float *s, *z; const int* ei;
  const float *wb1,*wb2,*wb3,*vb1,*vb2,*vb3,*eb1,*eb2,*eg,*ebb,*em,*ev;
  const u16* wt; float* aw; u16* av; float* zout;
};

__global__ __launch_bounds__(512,4) void edge_kernel(EdgeArgs A){
  __shared__ __align__(16) u16 SS[64*136];
  __shared__ __align__(16) u16 SD[64*136];
  __shared__ __align__(16) u16 ZB[64*72];
  __shared__ __align__(16) u16 HB[64*136];
  __shared__ __align__(16) u16 WT[128*64];
  const int tid = threadIdx.x, wave = tid>>6, lane = tid&63;
  const int lg = lane>>4, lr = lane&15;
  const int e0 = blockIdx.x*64;
  { // gather ss, sd, z -> bf16 LDS (8 threads/row)
    const int r = tid>>3, p = tid&7;
    const int sn = A.ei[e0 + r];
    const int dn = A.ei[NE + e0 + r];
    const float4* gs = (const float4*)(A.s + (size_t)sn*128 + p*16);
    float4 f0=gs[0], f1=gs[1], f2=gs[2], f3=gs[3];
    *(uint4*)(SS + r*136 + p*16)     = make_uint4(pk2(f0.x,f0.y),pk2(f0.z,f0.w),pk2(f1.x,f1.y),pk2(f1.z,f1.w));
    *(uint4*)(SS + r*136 + p*16 + 8) = make_uint4(pk2(f2.x,f2.y),pk2(f2.z,f2.w),pk2(f3.x,f3.y),pk2(f3.z,f3.w));
    const float4* gd = (const float4*)(A.s + (size_t)dn*128 + p*16);
    f0=gd[0]; f1=gd[1]; f2=gd[2]; f3=gd[3];
    *(uint4*)(SD + r*136 + p*16)     = make_uint4(pk2(f0.x,f0.y),pk2(f0.z,f0.w),pk2(f1.x,f1.y),pk2(f1.z,f1.w));
    *(uint4*)(SD + r*136 + p*16 + 8) = make_uint4(pk2(f2.x,f2.y),pk2(f2.z,f2.w),pk2(f3.x,f3.y),pk2(f3.z,f3.w));
    const float4* gz = (const float4*)(A.z + (size_t)(e0+r)*64 + p*8);
    float4 z0=gz[0], z1=gz[1];
    *(uint4*)(ZB + r*72 + p*8) = make_uint4(pk2(z0.x,z0.y),pk2(z0.z,z0.w),pk2(z1.x,z1.y),pk2(z1.z,z1.w));
  }
  int ntile, mt0; bool act_;
  { // e1: gelu([ss|sd|z] @ e_w1 + b)
    const u16* cb[5] = {SS,SS,SD,SD,ZB}; const int cs[5]={136,136,136,136,72}; const int ck[5]={0,64,0,64,0};
    f32x4 acc[4];
    run_gemm<5,8,4,4>(tid,wave,lane,cb,cs,ck, A.wt+WT_E1, WT, acc, ntile, mt0, act_);
    epi_hb<4>(acc, mt0, ntile, lg, lr, A.eb1, HB, 136, true);
  }
  { // e2: z_out = z + bn(h @ e_w2 + b); ZB <- bf16(z_out)
    const u16* cb[2] = {HB,HB}; const int cs[2]={136,136}; const int ck[2]={0,64};
    f32x4 acc[2];
    run_gemm<2,4,4,2>(tid,wave,lane,cb,cs,ck, A.wt+WT_E2, WT, acc, ntile, mt0, act_);
    const int col = ntile*16 + lr;
    const float b  = A.eb2[col];
    const float sc = A.eg[col] * rsqrtf(A.ev[col] + 1e-5f);
    const float sh = A.ebb[col] - A.em[col]*sc;
#pragma unroll
    for (int m=0;m<2;m++)
#pragma unroll
      for (int j=0;j<4;j++){
        int row = (mt0+m)*16 + lg*4 + j;
        float zo = A.z[(size_t)(e0+row)*64 + col];            // fp32 residual
        float zn = zo + (acc[m][j]+b)*sc + sh;
        A.zout[(size_t)(e0+row)*64 + col] = zn;
        ZB[row*72 + col] = f2bf(zn);
      }
  }
  { // w1: gelu([sd|ss|z'] @ w_w1 + b)
    const u16* cb[5] = {SD,SD,SS,SS,ZB}; const int cs[5]={136,136,136,136,72}; const int ck[5]={0,64,0,64,0};
    f32x4 acc[4];
    run_gemm<5,8,4,4>(tid,wave,lane,cb,cs,ck, A.wt+WT_W1, WT, acc, ntile, mt0, act_);
    epi_hb<4>(acc, mt0, ntile, lg, lr, A.wb1, HB, 136, true);
  }
  { // w2
    const u16* cb[2] = {HB,HB}; const int cs[2]={136,136}; const int ck[2]={0,64};
    f32x4 acc[4];
    run_gemm<2,8,4,4>(tid,wave,lane,cb,cs,ck, A.wt+WT_W2, WT, acc, ntile, mt0, act_);
    epi_hb<4>(acc, mt0, ntile, lg, lr, A.wb2, HB, 136, true);
  }
  { // w3: logits (Nout padded to 16, cols 0..3 valid) -> ws.aw fp32
    const u16* cb[2] = {HB,HB}; const int cs[2]={136,136}; const int ck[2]={0,64};
    f32x4 acc[1];
    run_gemm<2,1,4,1>(tid,wave,lane,cb,cs,ck, A.wt+WT_W3, WT, acc, ntile, mt0, act_);
    if (act_ && lr < 4){
      const float b = A.wb3[lr];
#pragma unroll
      for (int j=0;j<4;j++){
        int row = mt0*16 + lg*4 + j;
        A.aw[(size_t)(e0+row)*4 + lr] = acc[0][j] + b;
      }
    }
  }
  { // v1: gelu([ss|z'] @ v_w1 + b)
    const u16* cb[3] = {SS,SS,ZB}; const int cs[3]={136,136,72}; const int ck[3]={0,64,0};
    f32x4 acc[4];
    run_gemm<3,8,4,4>(tid,wave,lane,cb,cs,ck, A.wt+WT_V1, WT, acc, ntile, mt0, act_);
    epi_hb<4>(acc, mt0, ntile, lg, lr, A.vb1, HB, 136, true);
  }
  { // v2
    const u16* cb[2] = {HB,HB}; const int cs[2]={136,136}; const int ck[2]={0,64};
    f32x4 acc[4];
    run_gemm<2,8,4,4>(tid,wave,lane,cb,cs,ck, A.wt+WT_V2, WT, acc, ntile, mt0, act_);
    epi_hb<4>(acc, mt0, ntile, lg, lr, A.vb2, HB, 136, true);
  }
  { // v3: values -> ws.av bf16 (coalesced via LDS)
    const u16* cb[2] = {HB,HB}; const int cs[2]={136,136}; const int ck[2]={0,64};
    f32x4 acc[4];
    run_gemm<2,8,4,4>(tid,wave,lane,cb,cs,ck, A.wt+WT_V3, WT, acc, ntile, mt0, act_);
    epi_hb<4>(acc, mt0, ntile, lg, lr, A.vb3, HB, 136, false);
    __syncthreads();
    { const int r = tid>>3, p = tid&7;
      uint4 v0 = *(const uint4*)(HB + r*136 + p*16);
      uint4 v1 = *(const uint4*)(HB + r*136 + p*16 + 8);
      *(uint4*)(A.av + (size_t)(e0+r)*128 + p*16) = v0;
      *(uint4*)(A.av + (size_t)(e0+r)*128 + p*16 + 8) = v1; }
  }
}

// ---------------- segment softmax + weighted aggregate (atomic-free) ----------------
__global__ void attn_kernel(const float* __restrict__ aw, const u16* __restrict__ av,
                            const int* __restrict__ sta, const int* __restrict__ ord,
                            u16* __restrict__ ao){
  const int node = blockIdx.x; const int t = threadIdx.x; // 128 threads, t = feature d
  const int b = sta[node], e = sta[node+1];
  float m0=-3.4e38f, m1=m0, m2=m0, m3=m0;
  for (int i=b;i<e;i++){
    int ed = ord[i]; float4 a = *(const float4*)(aw + (size_t)ed*4);
    m0=fmaxf(m0,a.x); m1=fmaxf(m1,a.y); m2=fmaxf(m2,a.z); m3=fmaxf(m3,a.w);
  }
  float d0=0,d1=0,d2=0,d3=0,a0=0,a1=0,a2=0,a3=0;
  for (int i=b;i<e;i++){
    int ed = ord[i]; float4 a = *(const float4*)(aw + (size_t)ed*4);
    float w0=__expf(a.x-m0), w1=__expf(a.y-m1), w2=__expf(a.z-m2), w3=__expf(a.w-m3);
    d0+=w0; d1+=w1; d2+=w2; d3+=w3;
    float v = bf2f(av[(size_t)ed*128 + t]);
    a0 += w0*v; a1 += w1*v; a2 += w2*v; a3 += w3*v;
  }
  size_t o = (size_t)node*512 + t;
  if (e > b){
    ao[o      ] = f2bf(a0/d0);
    ao[o + 128] = f2bf(a1/d1);
    ao[o + 256] = f2bf(a2/d2);
    ao[o + 384] = f2bf(a3/d3);
  } else {
    ao[o] = 0; ao[o+128] = 0; ao[o+256] = 0; ao[o+384] = 0;
  }
}

// ---------------- node kernel ----------------
struct NodeArgs {
  const float* s; const u16* ao; const u16* wt;
  const float *ob,*og,*obb,*om,*ov,*fb1,*fb2,*fg,*fbb,*fm,*fv;
  float* outS;
};

__global__ __launch_bounds__(512,4) void node_kernel(NodeArgs A){
  __shared__ __align__(16) u16 AO[16*520];
  __shared__ __align__(16) u16 WT[128*64];
  __shared__ __align__(16) float S1F[16*128];
  __shared__ __align__(16) u16 S1B[16*136];
  __shared__ __align__(16) u16 HB2[16*136];
  const int tid=threadIdx.x, wave=tid>>6, lane=tid&63;
  const int lg=lane>>4, lr=lane&15;
  const int n0 = blockIdx.x*16;
  { const int r=tid>>5, p=tid&31;
    const uint4* gp = (const uint4*)(A.ao + (size_t)(n0+r)*512 + p*16);
    uint4 v0=gp[0], v1=gp[1];
    *(uint4*)(AO + r*520 + p*16) = v0;
    *(uint4*)(AO + r*520 + p*16 + 8) = v1;
  }
  int ntile, mt0; bool act_;
  float sc, sh, bb;
  { // s1 = s + bn(ao @ o_w + o_b)
    const u16* cb[8]={AO,AO,AO,AO,AO,AO,AO,AO};
    const int cs[8]={520,520,520,520,520,520,520,520};
    const int ck[8]={0,64,128,192,256,320,384,448};
    f32x4 acc[1];
    run_gemm<8,8,1,1>(tid,wave,lane,cb,cs,ck, A.wt+WT_O, WT, acc, ntile, mt0, act_);
    const int col = wave*16+lr;
    bb = A.ob[col];
    sc = A.og[col] * rsqrtf(A.ov[col] + 1e-5f);
    sh = A.obb[col] - A.om[col]*sc;
#pragma unroll
    for (int j=0;j<4;j++){
      int row = lg*4+j;
      float so = A.s[(size_t)(n0+row)*128 + col];
      float s1 = so + (acc[0][j]+bb)*sc + sh;
      S1F[row*128+col] = s1;
      S1B[row*136+col] = f2bf(s1);
    }
  }
  { // h = gelu(s1 @ f_w1 + b1)
    const u16* cb[2]={S1B,S1B}; const int cs[2]={136,136}; const int ck[2]={0,64};
    f32x4 acc[1];
    run_gemm<2,8,1,1>(tid,wave,lane,cb,cs,ck, A.wt+WT_F1, WT, acc, ntile, mt0, act_);
    epi_hb<1>(acc, 0, wave, lg, lr, A.fb1, HB2, 136, true);
  }
  { // out = s1 + bn(h @ f_w2 + b2), fp32 direct to global
    const u16* cb[2]={HB2,HB2}; const int cs[2]={136,136}; const int ck[2]={0,64};
    f32x4 acc[1];
    run_gemm<2,8,1,1>(tid,wave,lane,cb,cs,ck, A.wt+WT_F2, WT, acc, ntile, mt0, act_);
    const int col = wave*16+lr;
    const float b2  = A.fb2[col];
    const float sc2 = A.fg[col] * rsqrtf(A.fv[col] + 1e-5f);
    const float sh2 = A.fbb[col] - A.fm[col]*sc2;
#pragma unroll
    for (int j=0;j<4;j++){
      int row = lg*4+j;
      float v = S1F[row*128+col] + (acc[0][j]+b2)*sc2 + sh2;
      A.outS[(size_t)(n0+row)*128 + col] = v;
    }
  }
}

// ---------------- launch ----------------
extern "C" void kernel_launch(void* const* d_in, const int* in_sizes, int n_in,
                              void* d_out, int out_size, void* d_ws, size_t ws_size,
                              hipStream_t stream)
{
  const float* sG = (const float*)d_in[0];
  const float* zG = (const float*)d_in[1];
  const int* eiG = (const int*)d_in[2];
  char* ws = (char*)d_ws;
  u16*  wt  = (u16*)ws;
  float* aw = (float*)(ws + AW_B);
  u16*  av  = (u16*)(ws + AV_B);
  u16*  ao  = (u16*)(ws + AO_B);
  int* cnt = (int*)(ws + CNT_B);
  int* cur = (int*)(ws + CUR_B);
  int* sta = (int*)(ws + STA_B);
  int* ord = (int*)(ws + ORD_B);
  float* outS = (float*)d_out;
  float* outZ = outS + (size_t)NN*128;

  PrepArgs P;
  const int srcIdx[11] = {29,31,3,5,7,9,11,13,15,21,23}; // e1,e2,w1,w2,w3,v1,v2,v3,o,f1,f2
  for (int i=0;i<11;i++) P.src[i] = (const float*)d_in[srcIdx[i]];
  P.dst = wt;
  prep_kernel<<<dim3(1032), dim3(256), 0, stream>>>(P);
  zero_kernel<<<dim3((NN+255)/256), dim3(256), 0, stream>>>(cnt);
  hist_kernel<<<dim3((NE+255)/256), dim3(256), 0, stream>>>(eiG, cnt);
  scan_kernel<<<dim3(1), dim3(1024), 0, stream>>>(cnt, sta, cur);
  place_kernel<<<dim3((NE+255)/256), dim3(256), 0, stream>>>(eiG, cur, ord);

  EdgeArgs E;
  E.s = sG; E.z = zG; E.ei = eiG;
  E.wb1=(const float*)d_in[4];  E.wb2=(const float*)d_in[6];  E.wb3=(const float*)d_in[8];
  E.vb1=(const float*)d_in[10]; E.vb2=(const float*)d_in[12]; E.vb3=(const float*)d_in[14];
  E.eb1=(const float*)d_in[30]; E.eb2=(const float*)d_in[32];
  E.eg=(const float*)d_in[33]; E.ebb=(const float*)d_in[34]; E.em=(const float*)d_in[35]; E.ev=(const float*)d_in[36];
  E.wt = wt; E.aw = aw; E.av = av; E.zout = outZ;
  edge_kernel<<<dim3(NE/64), dim3(512), 0, stream>>>(E);

  attn_kernel<<<dim3(NN), dim3(128), 0, stream>>>(aw, av, sta, ord, ao);

  NodeArgs Nd;
  Nd.s = sG; Nd.ao = ao; Nd.wt = wt;
  Nd.ob=(const float*)d_in[16]; Nd.og=(const float*)d_in[17]; Nd.obb=(const float*)d_in[18];
  Nd.om=(const float*)d_in[19]; Nd.ov=(const float*)d_in[20];
  Nd.fb1=(const float*)d_in[22]; Nd.fb2=(const float*)d_in[24];
  Nd.fg=(const float*)d_in[25]; Nd.fbb=(const float*)d_in[26]; Nd.fm=(const float*)d_in[27]; Nd.fv=(const float*)d_in[28];
  Nd.outS = outS;
  node_kernel<<<dim3(NN/16), dim3(512), 0, stream>>>(Nd);
}

// Round 3
// 671.001 us; speedup vs baseline: 1.1347x; 1.1347x over previous
//
#include <hip/hip_runtime.h>
#include <stdint.h>

// MLPAttnGNN round 2: B-operand from global (L2) into registers -> no per-chunk
// barriers; tanh-GELU via v_exp; v_cvt_pk_bf16_f32 packing; coalesced prep;
// HB ping-pong. fp32 I/O, bf16 MFMA compute (layout verified by round-1 pass).

#define NN 20000
#define NE 320000

typedef unsigned short u16;
typedef __attribute__((ext_vector_type(8))) short bf16x8;
typedef __attribute__((ext_vector_type(4))) float f32x4;

__device__ __forceinline__ float bf2f(u16 u){ union{unsigned i; float f;} v; v.i=((unsigned)u)<<16; return v.f; }
__device__ __forceinline__ u16 f2bf(float f){ union{float f; unsigned i;} v; v.f=f; unsigned r = v.i + 0x7FFFu + ((v.i>>16)&1u); return (u16)(r>>16); }
__device__ __forceinline__ unsigned pk2(float a, float b){
  unsigned r; asm("v_cvt_pk_bf16_f32 %0, %1, %2" : "=v"(r) : "v"(a), "v"(b)); return r;
}
// tanh-form GELU (max |err| vs erf-GELU ~3e-3; margin is 0.031 -> 0.134)
__device__ __forceinline__ float gelu_f(float x){
  float y = 0.7978845608f*x*(1.0f + 0.044715f*x*x);
  float a = fabsf(y);
  float t = __expf(-2.0f*a);
  float th = (1.0f - t)*__builtin_amdgcn_rcpf(1.0f + t);
  th = copysignf(th, y);
  return 0.5f*x*(1.0f + th);
}

// ---- ws layout ----
// weight images (bf16), chunk-major [chunk][no][64] (NO swizzle)
#define WT_E1 0
#define WT_E2 40960
#define WT_W1 49152
#define WT_W2 90112
#define WT_W3 106496
#define WT_V1 108544
#define WT_V2 133120
#define WT_V3 149504
#define WT_O  165888
#define WT_F1 231424
#define WT_F2 247808
#define WT_TOT 264192
#define AW_B  ((size_t)WT_TOT*2)
#define AV_B  (AW_B + (size_t)NE*16)
#define AO_B  (AV_B + (size_t)NE*256)
#define CNT_B (AO_B + (size_t)NN*1024)
#define CUR_B (CNT_B + (size_t)NN*4)
#define STA_B (CUR_B + (size_t)NN*4)
#define ORD_B (STA_B + (size_t)(NN+1)*4 + 4)

// ---------------- weight prep: fp32 W[K][ns] -> [c][no][64] bf16, coalesced ----------------
struct PrepArgs { const float* src[11]; u16* dst; };

__global__ void prep_kernel(PrepArgs A){
  constexpr int NS[11]  = {128, 64,128,128,  4,128,128,128,128,128,128};
  constexpr int NO[11]  = {128, 64,128,128, 16,128,128,128,128,128,128};
  constexpr int OFF[11] = {0,40960,49152,90112,106496,108544,133120,149504,165888,231424,247808};
  constexpr int CUM[12] = {0,10,12,22,26,28,34,38,42,58,62,66};
  __shared__ float T[64][72];
  const int bid = blockIdx.x, t = threadIdx.x;
  int m = 0;
#pragma unroll
  for (int q=0;q<11;q++) if (bid >= CUM[q+1]) m = q+1;
  const int rel = bid - CUM[m];
  const int ntn = (NO[m] > 64) ? 2 : 1;
  const int c  = rel / ntn;
  const int nt = rel - c*ntn;
  const float* src = A.src[m];
  if (m != 4){
    const int k = t>>2, q = t&3;
    const float* sp = src + (size_t)(c*64+k)*NS[m] + nt*64 + q*16;
    float4 v0=((const float4*)sp)[0], v1=((const float4*)sp)[1], v2=((const float4*)sp)[2], v3=((const float4*)sp)[3];
    float* tp = &T[k][q*16];
    ((float4*)tp)[0]=v0; ((float4*)tp)[1]=v1; ((float4*)tp)[2]=v2; ((float4*)tp)[3]=v3;
  } else {
    for (int lin = t; lin < 64*16; lin += 256){
      int k = lin>>4, n = lin&15;
      T[k][n] = (n < 4) ? src[(size_t)(c*64+k)*4 + n] : 0.f;
    }
  }
  __syncthreads();
  const int nl = t>>2, kq = (t&3)*16;
  const int n = nt*64 + nl;
  if (nl < 64 && n < NO[m]){
    unsigned w[8];
#pragma unroll
    for (int i=0;i<8;i++) w[i] = pk2(T[kq+2*i][nl], T[kq+2*i+1][nl]);
    u16* dp = A.dst + OFF[m] + (size_t)c*NO[m]*64 + (size_t)n*64 + kq;
    ((uint4*)dp)[0] = make_uint4(w[0],w[1],w[2],w[3]);
    ((uint4*)dp)[1] = make_uint4(w[4],w[5],w[6],w[7]);
  }
}

// ---------------- CSR build ----------------
__global__ void zero_kernel(int* c){ int i = blockIdx.x*256+threadIdx.x; if (i<NN) c[i]=0; }
__global__ void hist_kernel(const int* __restrict__ ei, int* __restrict__ cnt){
  int e = blockIdx.x*256+threadIdx.x; if (e<NE) atomicAdd(&cnt[ei[NE+e]], 1);
}
__global__ void scan_kernel(const int* __restrict__ cnt, int* __restrict__ sta, int* __restrict__ cur){
  __shared__ int part[1024];
  const int t = threadIdx.x;
  const int base = t*20;
  int s = 0;
  for (int i=0;i<20;i++){ int idx=base+i; s += (idx<NN)?cnt[idx]:0; }
  part[t]=s; __syncthreads();
  for (int off=1; off<1024; off<<=1){
    int v = (t>=off)? part[t-off] : 0;
    __syncthreads();
    part[t] += v;
    __syncthreads();
  }
  int run = part[t] - s;
  for (int i=0;i<20;i++){ int idx=base+i; if (idx<NN){ int c=cnt[idx]; sta[idx]=run; cur[idx]=run; run+=c; } }
  if (t==1023) sta[NN] = part[1023];
}
__global__ void place_kernel(const int* __restrict__ ei, int* __restrict__ cur, int* __restrict__ ord){
  int e = blockIdx.x*256+threadIdx.x;
  if (e<NE){ int p = atomicAdd(&cur[ei[NE+e]], 1); ord[p]=e; }
}

// ---------------- MFMA stage: A from LDS, B from global (L2) with 1-chunk prefetch ----------------
template<int NCH, int NT, int MTT, int NACC>
__device__ __forceinline__ void run_gemm2(int wave, int lane,
    const u16* const (&cb)[NCH], const int (&cs)[NCH], const int (&ck)[NCH],
    const u16* __restrict__ wtG, f32x4 (&acc)[NACC],
    int& ntile, int& mt0, bool& active)
{
  const int lr = lane & 15, lg = lane >> 4;
  active = true;
  if (NT == 8){ ntile = wave; mt0 = 0; }
  else if (NT == 4){ ntile = wave & 3; mt0 = (wave >> 2) * NACC; }
  else { ntile = 0; mt0 = wave; active = (wave < MTT); }
  f32x4 z4 = {0.f,0.f,0.f,0.f};
#pragma unroll
  for (int m=0;m<NACC;m++) acc[m] = z4;
  if (!active) return;
  const int CE = NT*16*64;
  const u16* bp = wtG + (size_t)(ntile*16+lr)*64 + lg*8;
  bf16x8 bc0 = *(const bf16x8*)bp;
  bf16x8 bc1 = *(const bf16x8*)(bp + 32);
#pragma unroll
  for (int c=0;c<NCH;c++){
    bf16x8 bn0, bn1;
    if (c+1 < NCH){
      bn0 = *(const bf16x8*)(bp + (c+1)*CE);
      bn1 = *(const bf16x8*)(bp + (c+1)*CE + 32);
    }
#pragma unroll
    for (int m=0;m<NACC;m++){
      const u16* ap = cb[c] + (size_t)((mt0+m)*16 + lr)*cs[c] + ck[c] + lg*8;
      bf16x8 a0 = *(const bf16x8*)ap;
      bf16x8 a1 = *(const bf16x8*)(ap + 32);
      acc[m] = __builtin_amdgcn_mfma_f32_16x16x32_bf16(a0, bc0, acc[m], 0, 0, 0);
      acc[m] = __builtin_amdgcn_mfma_f32_16x16x32_bf16(a1, bc1, acc[m], 0, 0, 0);
    }
    bc0 = bn0; bc1 = bn1;
  }
}

template<int NACC>
__device__ __forceinline__ void epi_hb(const f32x4 (&acc)[NACC], int mt0, int ntile, int lg, int lr,
    const float* __restrict__ biasG, u16* dst, int dstride, bool act)
{
  const int col = ntile*16 + lr;
  const float b = biasG[col];
#pragma unroll
  for (int m=0;m<NACC;m++)
#pragma unroll
    for (int j=0;j<4;j++){
      int row = (mt0+m)*16 + lg*4 + j;
      float v = acc[m][j] + b;
      if (act) v = gelu_f(v);
      dst[row*dstride + col] = f2bf(v);
    }
}

// ---------------- edge mega-kernel ----------------
struct EdgeArgs {
  const float *s, *z; const int* ei;
  const float *wb1,*wb2,*wb3,*vb1,*vb2,*vb3,*eb1,*eb2,*eg,*ebb,*em,*ev;
  const u16* wt; float* aw; u16* av; float* zout;
};

__global__ __launch_bounds__(512,4) void edge_kernel(EdgeArgs A){
  __shared__ __align__(16) u16 SS[64*136];
  __shared__ __align__(16) u16 SD[64*136];
  __shared__ __align__(16) u16 ZB[64*88];
  __shared__ __align__(16) u16 HB1[64*136];
  __shared__ __align__(16) u16 HB2[64*136];
  const int tid = threadIdx.x, wave = tid>>6, lane = tid&63;
  const int lg = lane>>4, lr = lane&15;
  const int e0 = blockIdx.x*64;
  { // gather ss, sd, z -> bf16 LDS (8 threads/row)
    const int r = tid>>3, p = tid&7;
    const int sn = A.ei[e0 + r];
    const int dn = A.ei[NE + e0 + r];
    const float4* gs = (const float4*)(A.s + (size_t)sn*128 + p*16);
    float4 f0=gs[0], f1=gs[1], f2=gs[2], f3=gs[3];
    *(uint4*)(SS + r*136 + p*16)     = make_uint4(pk2(f0.x,f0.y),pk2(f0.z,f0.w),pk2(f1.x,f1.y),pk2(f1.z,f1.w));
    *(uint4*)(SS + r*136 + p*16 + 8) = make_uint4(pk2(f2.x,f2.y),pk2(f2.z,f2.w),pk2(f3.x,f3.y),pk2(f3.z,f3.w));
    const float4* gd = (const float4*)(A.s + (size_t)dn*128 + p*16);
    f0=gd[0]; f1=gd[1]; f2=gd[2]; f3=gd[3];
    *(uint4*)(SD + r*136 + p*16)     = make_uint4(pk2(f0.x,f0.y),pk2(f0.z,f0.w),pk2(f1.x,f1.y),pk2(f1.z,f1.w));
    *(uint4*)(SD + r*136 + p*16 + 8) = make_uint4(pk2(f2.x,f2.y),pk2(f2.z,f2.w),pk2(f3.x,f3.y),pk2(f3.z,f3.w));
    const float4* gz = (const float4*)(A.z + (size_t)(e0+r)*64 + p*8);
    float4 z0=gz[0], z1=gz[1];
    *(uint4*)(ZB + r*88 + p*8) = make_uint4(pk2(z0.x,z0.y),pk2(z0.z,z0.w),pk2(z1.x,z1.y),pk2(z1.z,z1.w));
  }
  __syncthreads();
  int ntile, mt0; bool act_;
  { // e1: gelu([ss|sd|z] @ e_w1 + b) -> HB1
    const u16* cb[5] = {SS,SS,SD,SD,ZB}; const int cs[5]={136,136,136,136,88}; const int ck[5]={0,64,0,64,0};
    f32x4 acc[4];
    run_gemm2<5,8,4,4>(wave,lane,cb,cs,ck, A.wt+WT_E1, acc, ntile, mt0, act_);
    epi_hb<4>(acc, mt0, ntile, lg, lr, A.eb1, HB1, 136, true);
  }
  __syncthreads();
  { // e2: z_out = z + bn(HB1 @ e_w2 + b); ZB <- bf16(z_out); zout global
    const u16* cb[2] = {HB1,HB1}; const int cs[2]={136,136}; const int ck[2]={0,64};
    f32x4 acc[2];
    run_gemm2<2,4,4,2>(wave,lane,cb,cs,ck, A.wt+WT_E2, acc, ntile, mt0, act_);
    const int col = ntile*16 + lr;
    const float b  = A.eb2[col];
    const float sc = A.eg[col] * rsqrtf(A.ev[col] + 1e-5f);
    const float sh = A.ebb[col] - A.em[col]*sc;
#pragma unroll
    for (int m=0;m<2;m++)
#pragma unroll
      for (int j=0;j<4;j++){
        int row = (mt0+m)*16 + lg*4 + j;
        float zo = A.z[(size_t)(e0+row)*64 + col];
        float zn = zo + (acc[m][j]+b)*sc + sh;
        A.zout[(size_t)(e0+row)*64 + col] = zn;
        ZB[row*88 + col] = f2bf(zn);
      }
  }
  __syncthreads();
  { // w1: gelu([sd|ss|z'] @ w_w1 + b) -> HB2
    const u16* cb[5] = {SD,SD,SS,SS,ZB}; const int cs[5]={136,136,136,136,88}; const int ck[5]={0,64,0,64,0};
    f32x4 acc[4];
    run_gemm2<5,8,4,4>(wave,lane,cb,cs,ck, A.wt+WT_W1, acc, ntile, mt0, act_);
    epi_hb<4>(acc, mt0, ntile, lg, lr, A.wb1, HB2, 136, true);
  }
  __syncthreads();
  { // w2: HB2 -> HB1
    const u16* cb[2] = {HB2,HB2}; const int cs[2]={136,136}; const int ck[2]={0,64};
    f32x4 acc[4];
    run_gemm2<2,8,4,4>(wave,lane,cb,cs,ck, A.wt+WT_W2, acc, ntile, mt0, act_);
    epi_hb<4>(acc, mt0, ntile, lg, lr, A.wb2, HB1, 136, true);
  }
  __syncthreads();
  { // w3: logits (padded no=16, cols 0..3 real) -> aw fp32 (no LDS writes)
    const u16* cb[2] = {HB1,HB1}; const int cs[2]={136,136}; const int ck[2]={0,64};
    f32x4 acc[1];
    run_gemm2<2,1,4,1>(wave,lane,cb,cs,ck, A.wt+WT_W3, acc, ntile, mt0, act_);
    if (act_ && lr < 4){
      const float b = A.wb3[lr];
#pragma unroll
      for (int j=0;j<4;j++){
        int row = mt0*16 + lg*4 + j;
        A.aw[(size_t)(e0+row)*4 + lr] = acc[0][j] + b;
      }
    }
  }
  { // v1: gelu([ss|z'] @ v_w1 + b) -> HB2 (HB2 free since post-w2 barrier)
    const u16* cb[3] = {SS,SS,ZB}; const int cs[3]={136,136,88}; const int ck[3]={0,64,0};
    f32x4 acc[4];
    run_gemm2<3,8,4,4>(wave,lane,cb,cs,ck, A.wt+WT_V1, acc, ntile, mt0, act_);
    epi_hb<4>(acc, mt0, ntile, lg, lr, A.vb1, HB2, 136, true);
  }
  __syncthreads();
  { // v2: HB2 -> HB1
    const u16* cb[2] = {HB2,HB2}; const int cs[2]={136,136}; const int ck[2]={0,64};
    f32x4 acc[4];
    run_gemm2<2,8,4,4>(wave,lane,cb,cs,ck, A.wt+WT_V2, acc, ntile, mt0, act_);
    epi_hb<4>(acc, mt0, ntile, lg, lr, A.vb2, HB1, 136, true);
  }
  __syncthreads();
  { // v3: HB1 -> HB2 (values), then coalesced store
    const u16* cb[2] = {HB1,HB1}; const int cs[2]={136,136}; const int ck[2]={0,64};
    f32x4 acc[4];
    run_gemm2<2,8,4,4>(wave,lane,cb,cs,ck, A.wt+WT_V3, acc, ntile, mt0, act_);
    epi_hb<4>(acc, mt0, ntile, lg, lr, A.vb3, HB2, 136, false);
    __syncthreads();
    { const int r = tid>>3, p = tid&7;
      uint4 v0 = *(const uint4*)(HB2 + r*136 + p*16);
      uint4 v1 = *(const uint4*)(HB2 + r*136 + p*16 + 8);
      *(uint4*)(A.av + (size_t)(e0+r)*128 + p*16) = v0;
      *(uint4*)(A.av + (size_t)(e0+r)*128 + p*16 + 8) = v1; }
  }
}

// ---------------- segment softmax + weighted aggregate (atomic-free) ----------------
__global__ void attn_kernel(const float* __restrict__ aw, const u16* __restrict__ av,
                            const int* __restrict__ sta, const int* __restrict__ ord,
                            u16* __restrict__ ao){
  const int node = blockIdx.x; const int t = threadIdx.x; // 128 threads, t = feature d
  const int b = sta[node], e = sta[node+1];
  float m0=-3.4e38f, m1=m0, m2=m0, m3=m0;
  for (int i=b;i<e;i++){
    int ed = ord[i]; float4 a = *(const float4*)(aw + (size_t)ed*4);
    m0=fmaxf(m0,a.x); m1=fmaxf(m1,a.y); m2=fmaxf(m2,a.z); m3=fmaxf(m3,a.w);
  }
  float d0=0,d1=0,d2=0,d3=0,a0=0,a1=0,a2=0,a3=0;
  for (int i=b;i<e;i++){
    int ed = ord[i]; float4 a = *(const float4*)(aw + (size_t)ed*4);
    float w0=__expf(a.x-m0), w1=__expf(a.y-m1), w2=__expf(a.z-m2), w3=__expf(a.w-m3);
    d0+=w0; d1+=w1; d2+=w2; d3+=w3;
    float v = bf2f(av[(size_t)ed*128 + t]);
    a0 += w0*v; a1 += w1*v; a2 += w2*v; a3 += w3*v;
  }
  size_t o = (size_t)node*512 + t;
  if (e > b){
    ao[o      ] = f2bf(a0/d0);
    ao[o + 128] = f2bf(a1/d1);
    ao[o + 256] = f2bf(a2/d2);
    ao[o + 384] = f2bf(a3/d3);
  } else {
    ao[o] = 0; ao[o+128] = 0; ao[o+256] = 0; ao[o+384] = 0;
  }
}

// ---------------- node kernel ----------------
struct NodeArgs {
  const float* s; const u16* ao; const u16* wt;
  const float *ob,*og,*obb,*om,*ov,*fb1,*fb2,*fg,*fbb,*fm,*fv;
  float* outS;
};

__global__ __launch_bounds__(512,4) void node_kernel(NodeArgs A){
  __shared__ __align__(16) u16 AO[16*520];
  __shared__ __align__(16) float S1F[16*128];
  __shared__ __align__(16) u16 S1B[16*136];
  __shared__ __align__(16) u16 HBx[16*136];
  const int tid=threadIdx.x, wave=tid>>6, lane=tid&63;
  const int lg=lane>>4, lr=lane&15;
  const int n0 = blockIdx.x*16;
  { const int r=tid>>5, p=tid&31;
    const uint4* gp = (const uint4*)(A.ao + (size_t)(n0+r)*512 + p*16);
    uint4 v0=gp[0], v1=gp[1];
    *(uint4*)(AO + r*520 + p*16) = v0;
    *(uint4*)(AO + r*520 + p*16 + 8) = v1;
  }
  __syncthreads();
  int ntile, mt0; bool act_;
  { // s1 = s + bn(ao @ o_w + o_b)
    const u16* cb[8]={AO,AO,AO,AO,AO,AO,AO,AO};
    const int cs[8]={520,520,520,520,520,520,520,520};
    const int ck[8]={0,64,128,192,256,320,384,448};
    f32x4 acc[1];
    run_gemm2<8,8,1,1>(wave,lane,cb,cs,ck, A.wt+WT_O, acc, ntile, mt0, act_);
    const int col = wave*16+lr;
    const float bb = A.ob[col];
    const float sc = A.og[col] * rsqrtf(A.ov[col] + 1e-5f);
    const float sh = A.obb[col] - A.om[col]*sc;
#pragma unroll
    for (int j=0;j<4;j++){
      int row = lg*4+j;
      float so = A.s[(size_t)(n0+row)*128 + col];
      float s1 = so + (acc[0][j]+bb)*sc + sh;
      S1F[row*128+col] = s1;
      S1B[row*136+col] = f2bf(s1);
    }
  }
  __syncthreads();
  { // h = gelu(s1 @ f_w1 + b1) -> HBx
    const u16* cb[2]={S1B,S1B}; const int cs[2]={136,136}; const int ck[2]={0,64};
    f32x4 acc[1];
    run_gemm2<2,8,1,1>(wave,lane,cb,cs,ck, A.wt+WT_F1, acc, ntile, mt0, act_);
    epi_hb<1>(acc, 0, wave, lg, lr, A.fb1, HBx, 136, true);
  }
  __syncthreads();
  { // out = s1 + bn(h @ f_w2 + b2) -> global fp32
    const u16* cb[2]={HBx,HBx}; const int cs[2]={136,136}; const int ck[2]={0,64};
    f32x4 acc[1];
    run_gemm2<2,8,1,1>(wave,lane,cb,cs,ck, A.wt+WT_F2, acc, ntile, mt0, act_);
    const int col = wave*16+lr;
    const float b2  = A.fb2[col];
    const float sc2 = A.fg[col] * rsqrtf(A.fv[col] + 1e-5f);
    const float sh2 = A.fbb[col] - A.fm[col]*sc2;
#pragma unroll
    for (int j=0;j<4;j++){
      int row = lg*4+j;
      float v = S1F[row*128+col] + (acc[0][j]+b2)*sc2 + sh2;
      A.outS[(size_t)(n0+row)*128 + col] = v;
    }
  }
}

// ---------------- launch ----------------
extern "C" void kernel_launch(void* const* d_in, const int* in_sizes, int n_in,
                              void* d_out, int out_size, void* d_ws, size_t ws_size,
                              hipStream_t stream)
{
  const float* sG = (const float*)d_in[0];
  const float* zG = (const float*)d_in[1];
  const int* eiG = (const int*)d_in[2];
  char* ws = (char*)d_ws;
  u16*  wt  = (u16*)ws;
  float* aw = (float*)(ws + AW_B);
  u16*  av  = (u16*)(ws + AV_B);
  u16*  ao  = (u16*)(ws + AO_B);
  int* cnt = (int*)(ws + CNT_B);
  int* cur = (int*)(ws + CUR_B);
  int* sta = (int*)(ws + STA_B);
  int* ord = (int*)(ws + ORD_B);
  float* outS = (float*)d_out;
  float* outZ = outS + (size_t)NN*128;

  PrepArgs P;
  const int srcIdx[11] = {29,31,3,5,7,9,11,13,15,21,23}; // e1,e2,w1,w2,w3,v1,v2,v3,o,f1,f2
  for (int i=0;i<11;i++) P.src[i] = (const float*)d_in[srcIdx[i]];
  P.dst = wt;
  prep_kernel<<<dim3(66), dim3(256), 0, stream>>>(P);
  zero_kernel<<<dim3((NN+255)/256), dim3(256), 0, stream>>>(cnt);
  hist_kernel<<<dim3((NE+255)/256), dim3(256), 0, stream>>>(eiG, cnt);
  scan_kernel<<<dim3(1), dim3(1024), 0, stream>>>(cnt, sta, cur);
  place_kernel<<<dim3((NE+255)/256), dim3(256), 0, stream>>>(eiG, cur, ord);

  EdgeArgs E;
  E.s = sG; E.z = zG; E.ei = eiG;
  E.wb1=(const float*)d_in[4];  E.wb2=(const float*)d_in[6];  E.wb3=(const float*)d_in[8];
  E.vb1=(const float*)d_in[10]; E.vb2=(const float*)d_in[12]; E.vb3=(const float*)d_in[14];
  E.eb1=(const float*)d_in[30]; E.eb2=(const float*)d_in[32];
  E.eg=(const float*)d_in[33]; E.ebb=(const float*)d_in[34]; E.em=(const float*)d_in[35]; E.ev=(const float*)d_in[36];
  E.wt = wt; E.aw = aw; E.av = av; E.zout = outZ;
  edge_kernel<<<dim3(NE/64), dim3(512), 0, stream>>>(E);

  attn_kernel<<<dim3(NN), dim3(128), 0, stream>>>(aw, av, sta, ord, ao);

  NodeArgs Nd;
  Nd.s = sG; Nd.ao = ao; Nd.wt = wt;
  Nd.ob=(const float*)d_in[16]; Nd.og=(const float*)d_in[17]; Nd.obb=(const float*)d_in[18];
  Nd.om=(const float*)d_in[19]; Nd.ov=(const float*)d_in[20];
  Nd.fb1=(const float*)d_in[22]; Nd.fb2=(const float*)d_in[24];
  Nd.fg=(const float*)d_in[25]; Nd.fbb=(const float*)d_in[26]; Nd.fm=(const float*)d_in[27]; Nd.fv=(const float*)d_in[28];
  Nd.outS = outS;
  node_kernel<<<dim3(NN/16), dim3(512), 0, stream>>>(Nd);
}

// Round 4
// 670.282 us; speedup vs baseline: 1.1360x; 1.0011x over previous
//
#include <hip/hip_runtime.h>
#include <stdint.h>

// MLPAttnGNN round 3: (1) per-stage B-fragments fully hoisted to registers
// (breaks the 1-deep prefetch chain -> one L2 latency per stage, not per chunk);
// (2) attention softmax-aggregate fused into node_kernel (no ao round-trip);
// (3) fewer launches: memset + setup(prep|hist) + scan + place + edge + node.

#define NN 20000
#define NE 320000

typedef unsigned short u16;
typedef __attribute__((ext_vector_type(8))) short bf16x8;
typedef __attribute__((ext_vector_type(4))) float f32x4;

__device__ __forceinline__ float bf2f(u16 u){ union{unsigned i; float f;} v; v.i=((unsigned)u)<<16; return v.f; }
__device__ __forceinline__ u16 f2bf(float f){ union{float f; unsigned i;} v; v.f=f; unsigned r = v.i + 0x7FFFu + ((v.i>>16)&1u); return (u16)(r>>16); }
__device__ __forceinline__ unsigned pk2(float a, float b){
  unsigned r; asm("v_cvt_pk_bf16_f32 %0, %1, %2" : "=v"(r) : "v"(a), "v"(b)); return r;
}
// tanh-form GELU (max |err| vs erf-GELU ~3e-3; abs margin 0.031 -> 0.134)
__device__ __forceinline__ float gelu_f(float x){
  float y = 0.7978845608f*x*(1.0f + 0.044715f*x*x);
  float a = fabsf(y);
  float t = __expf(-2.0f*a);
  float th = (1.0f - t)*__builtin_amdgcn_rcpf(1.0f + t);
  th = copysignf(th, y);
  return 0.5f*x*(1.0f + th);
}

// ---- ws layout ----
#define WT_E1 0
#define WT_E2 40960
#define WT_W1 49152
#define WT_W2 90112
#define WT_W3 106496
#define WT_V1 108544
#define WT_V2 133120
#define WT_V3 149504
#define WT_O  165888
#define WT_F1 231424
#define WT_F2 247808
#define WT_TOT 264192
#define AW_B  ((size_t)WT_TOT*2)
#define AV_B  (AW_B + (size_t)NE*16)
#define CNT_B (AV_B + (size_t)NE*256)
#define CUR_B (CNT_B + (size_t)NN*4)
#define STA_B (CUR_B + (size_t)NN*4)
#define ORD_B (STA_B + (size_t)(NN+1)*4 + 4)

// ---------------- setup: prep (blocks 0..65) | hist (blocks 66..) ----------------
struct PrepArgs { const float* src[11]; u16* dst; };

__global__ void setup_kernel(PrepArgs A, const int* __restrict__ ei, int* __restrict__ cnt){
  constexpr int NS[11]  = {128, 64,128,128,  4,128,128,128,128,128,128};
  constexpr int NO[11]  = {128, 64,128,128, 16,128,128,128,128,128,128};
  constexpr int OFF[11] = {0,40960,49152,90112,106496,108544,133120,149504,165888,231424,247808};
  constexpr int CUM[12] = {0,10,12,22,26,28,34,38,42,58,62,66};
  __shared__ float T[64][72];
  const int t = threadIdx.x;
  if (blockIdx.x >= 66){
    int e = (blockIdx.x-66)*256 + t;
    if (e < NE) atomicAdd(&cnt[ei[NE+e]], 1);
    return;
  }
  const int bid = blockIdx.x;
  int m = 0;
#pragma unroll
  for (int q=0;q<11;q++) if (bid >= CUM[q+1]) m = q+1;
  const int rel = bid - CUM[m];
  const int ntn = (NO[m] > 64) ? 2 : 1;
  const int c  = rel / ntn;
  const int nt = rel - c*ntn;
  const float* src = A.src[m];
  if (m != 4){
    const int k = t>>2, q = t&3;
    const float* sp = src + (size_t)(c*64+k)*NS[m] + nt*64 + q*16;
    float4 v0=((const float4*)sp)[0], v1=((const float4*)sp)[1], v2=((const float4*)sp)[2], v3=((const float4*)sp)[3];
    float* tp = &T[k][q*16];
    ((float4*)tp)[0]=v0; ((float4*)tp)[1]=v1; ((float4*)tp)[2]=v2; ((float4*)tp)[3]=v3;
  } else {
    for (int lin = t; lin < 64*16; lin += 256){
      int k = lin>>4, n = lin&15;
      T[k][n] = (n < 4) ? src[(size_t)(c*64+k)*4 + n] : 0.f;
    }
  }
  __syncthreads();
  const int nl = t>>2, kq = (t&3)*16;
  const int n = nt*64 + nl;
  if (nl < 64 && n < NO[m]){
    unsigned w[8];
#pragma unroll
    for (int i=0;i<8;i++) w[i] = pk2(T[kq+2*i][nl], T[kq+2*i+1][nl]);
    u16* dp = A.dst + OFF[m] + (size_t)c*NO[m]*64 + (size_t)n*64 + kq;
    ((uint4*)dp)[0] = make_uint4(w[0],w[1],w[2],w[3]);
    ((uint4*)dp)[1] = make_uint4(w[4],w[5],w[6],w[7]);
  }
}

// ---------------- CSR scan + place ----------------
__global__ void scan_kernel(const int* __restrict__ cnt, int* __restrict__ sta, int* __restrict__ cur){
  __shared__ int part[1024];
  const int t = threadIdx.x;
  const int base = t*20;
  int v[20];
  int s = 0;
  if (t < 1000){
#pragma unroll
    for (int i=0;i<5;i++){
      int4 x = ((const int4*)(cnt+base))[i];
      v[4*i]=x.x; v[4*i+1]=x.y; v[4*i+2]=x.z; v[4*i+3]=x.w;
      s += x.x+x.y+x.z+x.w;
    }
  }
  part[t]=s; __syncthreads();
  for (int off=1; off<1024; off<<=1){
    int x = (t>=off)? part[t-off] : 0;
    __syncthreads();
    part[t] += x;
    __syncthreads();
  }
  int run = part[t] - s;
  if (t < 1000){
    int sv[20];
#pragma unroll
    for (int i=0;i<20;i++){ sv[i]=run; run += v[i]; }
#pragma unroll
    for (int i=0;i<5;i++){
      int4 x = make_int4(sv[4*i],sv[4*i+1],sv[4*i+2],sv[4*i+3]);
      ((int4*)(sta+base))[i] = x;
      ((int4*)(cur+base))[i] = x;
    }
  }
  if (t==1023) sta[NN] = part[1023];
}
__global__ void place_kernel(const int* __restrict__ ei, int* __restrict__ cur, int* __restrict__ ord){
  int e = blockIdx.x*256+threadIdx.x;
  if (e<NE){ int p = atomicAdd(&cur[ei[NE+e]], 1); ord[p]=e; }
}

// ---------------- MFMA stage: A from LDS, ALL B-fragments hoisted to regs ----------------
template<int NCH, int NT, int MTT, int NACC>
__device__ __forceinline__ void run_gemm3(int wave, int lane,
    const u16* const (&cb)[NCH], const int (&cs)[NCH], const int (&ck)[NCH],
    const u16* __restrict__ wtG, f32x4 (&acc)[NACC],
    int& ntile, int& mt0, bool& active)
{
  const int lr = lane & 15, lg = lane >> 4;
  active = true;
  if (NT == 8){ ntile = wave; mt0 = 0; }
  else if (NT == 4){ ntile = wave & 3; mt0 = (wave >> 2) * NACC; }
  else { ntile = 0; mt0 = wave; active = (wave < MTT); }
  f32x4 z4 = {0.f,0.f,0.f,0.f};
#pragma unroll
  for (int m=0;m<NACC;m++) acc[m] = z4;
  if (!active) return;
  const int CE = NT*16*64;
  const u16* bp = wtG + (size_t)(ntile*16+lr)*64 + lg*8;
  bf16x8 B0[NCH], B1[NCH];
#pragma unroll
  for (int c=0;c<NCH;c++){
    B0[c] = *(const bf16x8*)(bp + (size_t)c*CE);
    B1[c] = *(const bf16x8*)(bp + (size_t)c*CE + 32);
  }
#pragma unroll
  for (int c=0;c<NCH;c++){
#pragma unroll
    for (int m=0;m<NACC;m++){
      const u16* ap = cb[c] + (size_t)((mt0+m)*16 + lr)*cs[c] + ck[c] + lg*8;
      bf16x8 a0 = *(const bf16x8*)ap;
      bf16x8 a1 = *(const bf16x8*)(ap + 32);
      acc[m] = __builtin_amdgcn_mfma_f32_16x16x32_bf16(a0, B0[c], acc[m], 0, 0, 0);
      acc[m] = __builtin_amdgcn_mfma_f32_16x16x32_bf16(a1, B1[c], acc[m], 0, 0, 0);
    }
  }
}

template<int NACC>
__device__ __forceinline__ void epi_hb(const f32x4 (&acc)[NACC], int mt0, int ntile, int lg, int lr,
    const float* __restrict__ biasG, u16* dst, int dstride, bool act)
{
  const int col = ntile*16 + lr;
  const float b = biasG[col];
#pragma unroll
  for (int m=0;m<NACC;m++)
#pragma unroll
    for (int j=0;j<4;j++){
      int row = (mt0+m)*16 + lg*4 + j;
      float v = acc[m][j] + b;
      if (act) v = gelu_f(v);
      dst[row*dstride + col] = f2bf(v);
    }
}

// ---------------- edge mega-kernel ----------------
struct EdgeArgs {
  const float *s, *z; const int* ei;
  const float *wb1,*wb2,*wb3,*vb1,*vb2,*vb3,*eb1,*eb2,*eg,*ebb,*em,*ev;
  const u16* wt; float* aw; u16* av; float* zout;
};

__global__ __launch_bounds__(512,4) void edge_kernel(EdgeArgs A){
  __shared__ __align__(16) u16 SS[64*136];
  __shared__ __align__(16) u16 SD[64*136];
  __shared__ __align__(16) u16 ZB[64*72];
  __shared__ __align__(16) u16 HB1[64*136];
  __shared__ __align__(16) u16 HB2[64*136];
  const int tid = threadIdx.x, wave = tid>>6, lane = tid&63;
  const int lg = lane>>4, lr = lane&15;
  const int e0 = blockIdx.x*64;
  { // gather ss, sd, z -> bf16 LDS (8 threads/row)
    const int r = tid>>3, p = tid&7;
    const int sn = A.ei[e0 + r];
    const int dn = A.ei[NE + e0 + r];
    const float4* gs = (const float4*)(A.s + (size_t)sn*128 + p*16);
    float4 f0=gs[0], f1=gs[1], f2=gs[2], f3=gs[3];
    *(uint4*)(SS + r*136 + p*16)     = make_uint4(pk2(f0.x,f0.y),pk2(f0.z,f0.w),pk2(f1.x,f1.y),pk2(f1.z,f1.w));
    *(uint4*)(SS + r*136 + p*16 + 8) = make_uint4(pk2(f2.x,f2.y),pk2(f2.z,f2.w),pk2(f3.x,f3.y),pk2(f3.z,f3.w));
    const float4* gd = (const float4*)(A.s + (size_t)dn*128 + p*16);
    f0=gd[0]; f1=gd[1]; f2=gd[2]; f3=gd[3];
    *(uint4*)(SD + r*136 + p*16)     = make_uint4(pk2(f0.x,f0.y),pk2(f0.z,f0.w),pk2(f1.x,f1.y),pk2(f1.z,f1.w));
    *(uint4*)(SD + r*136 + p*16 + 8) = make_uint4(pk2(f2.x,f2.y),pk2(f2.z,f2.w),pk2(f3.x,f3.y),pk2(f3.z,f3.w));
    const float4* gz = (const float4*)(A.z + (size_t)(e0+r)*64 + p*8);
    float4 z0=gz[0], z1=gz[1];
    *(uint4*)(ZB + r*72 + p*8) = make_uint4(pk2(z0.x,z0.y),pk2(z0.z,z0.w),pk2(z1.x,z1.y),pk2(z1.z,z1.w));
  }
  __syncthreads();
  int ntile, mt0; bool act_;
  { // e1: gelu([ss|sd|z] @ e_w1 + b) -> HB1
    const u16* cb[5] = {SS,SS,SD,SD,ZB}; const int cs[5]={136,136,136,136,72}; const int ck[5]={0,64,0,64,0};
    f32x4 acc[4];
    run_gemm3<5,8,4,4>(wave,lane,cb,cs,ck, A.wt+WT_E1, acc, ntile, mt0, act_);
    epi_hb<4>(acc, mt0, ntile, lg, lr, A.eb1, HB1, 136, true);
  }
  __syncthreads();
  { // e2: z_out = z + bn(HB1 @ e_w2 + b); ZB <- bf16(z_out); zout global
    const u16* cb[2] = {HB1,HB1}; const int cs[2]={136,136}; const int ck[2]={0,64};
    f32x4 acc[2];
    run_gemm3<2,4,4,2>(wave,lane,cb,cs,ck, A.wt+WT_E2, acc, ntile, mt0, act_);
    const int col = ntile*16 + lr;
    const float b  = A.eb2[col];
    const float sc = A.eg[col] * rsqrtf(A.ev[col] + 1e-5f);
    const float sh = A.ebb[col] - A.em[col]*sc;
#pragma unroll
    for (int m=0;m<2;m++)
#pragma unroll
      for (int j=0;j<4;j++){
        int row = (mt0+m)*16 + lg*4 + j;
        float zo = A.z[(size_t)(e0+row)*64 + col];
        float zn = zo + (acc[m][j]+b)*sc + sh;
        A.zout[(size_t)(e0+row)*64 + col] = zn;
        ZB[row*72 + col] = f2bf(zn);
      }
  }
  __syncthreads();
  { // w1: gelu([sd|ss|z'] @ w_w1 + b) -> HB2
    const u16* cb[5] = {SD,SD,SS,SS,ZB}; const int cs[5]={136,136,136,136,72}; const int ck[5]={0,64,0,64,0};
    f32x4 acc[4];
    run_gemm3<5,8,4,4>(wave,lane,cb,cs,ck, A.wt+WT_W1, acc, ntile, mt0, act_);
    epi_hb<4>(acc, mt0, ntile, lg, lr, A.wb1, HB2, 136, true);
  }
  __syncthreads();
  { // w2: HB2 -> HB1
    const u16* cb[2] = {HB2,HB2}; const int cs[2]={136,136}; const int ck[2]={0,64};
    f32x4 acc[4];
    run_gemm3<2,8,4,4>(wave,lane,cb,cs,ck, A.wt+WT_W2, acc, ntile, mt0, act_);
    epi_hb<4>(acc, mt0, ntile, lg, lr, A.wb2, HB1, 136, true);
  }
  __syncthreads();
  { // w3: logits (padded no=16, cols 0..3 real) -> aw fp32
    const u16* cb[2] = {HB1,HB1}; const int cs[2]={136,136}; const int ck[2]={0,64};
    f32x4 acc[1];
    run_gemm3<2,1,4,1>(wave,lane,cb,cs,ck, A.wt+WT_W3, acc, ntile, mt0, act_);
    if (act_ && lr < 4){
      const float b = A.wb3[lr];
#pragma unroll
      for (int j=0;j<4;j++){
        int row = mt0*16 + lg*4 + j;
        A.aw[(size_t)(e0+row)*4 + lr] = acc[0][j] + b;
      }
    }
  }
  { // v1: gelu([ss|z'] @ v_w1 + b) -> HB2
    const u16* cb[3] = {SS,SS,ZB}; const int cs[3]={136,136,72}; const int ck[3]={0,64,0};
    f32x4 acc[4];
    run_gemm3<3,8,4,4>(wave,lane,cb,cs,ck, A.wt+WT_V1, acc, ntile, mt0, act_);
    epi_hb<4>(acc, mt0, ntile, lg, lr, A.vb1, HB2, 136, true);
  }
  __syncthreads();
  { // v2: HB2 -> HB1
    const u16* cb[2] = {HB2,HB2}; const int cs[2]={136,136}; const int ck[2]={0,64};
    f32x4 acc[4];
    run_gemm3<2,8,4,4>(wave,lane,cb,cs,ck, A.wt+WT_V2, acc, ntile, mt0, act_);
    epi_hb<4>(acc, mt0, ntile, lg, lr, A.vb2, HB1, 136, true);
  }
  __syncthreads();
  { // v3: HB1 -> HB2 (values), coalesced store
    const u16* cb[2] = {HB1,HB1}; const int cs[2]={136,136}; const int ck[2]={0,64};
    f32x4 acc[4];
    run_gemm3<2,8,4,4>(wave,lane,cb,cs,ck, A.wt+WT_V3, acc, ntile, mt0, act_);
    epi_hb<4>(acc, mt0, ntile, lg, lr, A.vb3, HB2, 136, false);
    __syncthreads();
    { const int r = tid>>3, p = tid&7;
      uint4 v0 = *(const uint4*)(HB2 + r*136 + p*16);
      uint4 v1 = *(const uint4*)(HB2 + r*136 + p*16 + 8);
      *(uint4*)(A.av + (size_t)(e0+r)*128 + p*16) = v0;
      *(uint4*)(A.av + (size_t)(e0+r)*128 + p*16 + 8) = v1; }
  }
}

// ---------------- node kernel: fused attn-aggregate + o-proj + FFN ----------------
struct NodeArgs {
  const float* s; const float* aw; const u16* av;
  const int* sta; const int* ord; const u16* wt;
  const float *ob,*og,*obb,*om,*ov,*fb1,*fb2,*fg,*fbb,*fm,*fv;
  float* outS;
};

__global__ __launch_bounds__(512,4) void node_kernel(NodeArgs A){
  __shared__ __align__(16) u16 AO[16*520];
  __shared__ __align__(16) float S1F[16*128];
  __shared__ __align__(16) u16 S1B[16*136];
  __shared__ __align__(16) u16 HBx[16*136];
  const int tid=threadIdx.x, wave=tid>>6, lane=tid&63;
  const int lg=lane>>4, lr=lane&15;
  const int n0 = blockIdx.x*16;
  // ---- segment softmax + weighted aggregate: wave w -> local rows 2w, 2w+1 ----
#pragma unroll
  for (int q=0;q<2;q++){
    const int lrow = wave*2+q, nn = n0+lrow;
    const int b = A.sta[nn], e = A.sta[nn+1];
    float m0=-3.4e38f, m1=m0, m2=m0, m3=m0;
    for (int i=b;i<e;i++){
      int ed = A.ord[i];
      float4 a = *(const float4*)(A.aw + (size_t)ed*4);
      m0=fmaxf(m0,a.x); m1=fmaxf(m1,a.y); m2=fmaxf(m2,a.z); m3=fmaxf(m3,a.w);
    }
    float d0=0,d1=0,d2=0,d3=0;
    float a00=0,a01=0,a10=0,a11=0,a20=0,a21=0,a30=0,a31=0;
    for (int i=b;i<e;i++){
      int ed = A.ord[i];
      float4 a = *(const float4*)(A.aw + (size_t)ed*4);
      float w0=__expf(a.x-m0), w1=__expf(a.y-m1), w2=__expf(a.z-m2), w3=__expf(a.w-m3);
      d0+=w0; d1+=w1; d2+=w2; d3+=w3;
      unsigned pv = *(const unsigned*)(A.av + (size_t)ed*128 + lane*2);
      float v0 = bf2f((u16)pv), v1 = bf2f((u16)(pv>>16));
      a00+=w0*v0; a01+=w0*v1; a10+=w1*v0; a11+=w1*v1;
      a20+=w2*v0; a21+=w2*v1; a30+=w3*v0; a31+=w3*v1;
    }
    unsigned* aoRow = (unsigned*)(AO + lrow*520);
    if (e > b){
      float r0=1.f/d0, r1=1.f/d1, r2=1.f/d2, r3=1.f/d3;
      aoRow[        lane] = pk2(a00*r0, a01*r0);
      aoRow[ 64 + lane] = pk2(a10*r1, a11*r1);
      aoRow[128 + lane] = pk2(a20*r2, a21*r2);
      aoRow[192 + lane] = pk2(a30*r3, a31*r3);
    } else {
      aoRow[lane]=0; aoRow[64+lane]=0; aoRow[128+lane]=0; aoRow[192+lane]=0;
    }
  }
  __syncthreads();
  int ntile, mt0; bool act_;
  { // s1 = s + bn(ao @ o_w + o_b)
    const u16* cb[8]={AO,AO,AO,AO,AO,AO,AO,AO};
    const int cs[8]={520,520,520,520,520,520,520,520};
    const int ck[8]={0,64,128,192,256,320,384,448};
    f32x4 acc[1];
    run_gemm3<8,8,1,1>(wave,lane,cb,cs,ck, A.wt+WT_O, acc, ntile, mt0, act_);
    const int col = wave*16+lr;
    const float bb = A.ob[col];
    const float sc = A.og[col] * rsqrtf(A.ov[col] + 1e-5f);
    const float sh = A.obb[col] - A.om[col]*sc;
#pragma unroll
    for (int j=0;j<4;j++){
      int row = lg*4+j;
      float so = A.s[(size_t)(n0+row)*128 + col];
      float s1 = so + (acc[0][j]+bb)*sc + sh;
      S1F[row*128+col] = s1;
      S1B[row*136+col] = f2bf(s1);
    }
  }
  __syncthreads();
  { // h = gelu(s1 @ f_w1 + b1) -> HBx
    const u16* cb[2]={S1B,S1B}; const int cs[2]={136,136}; const int ck[2]={0,64};
    f32x4 acc[1];
    run_gemm3<2,8,1,1>(wave,lane,cb,cs,ck, A.wt+WT_F1, acc, ntile, mt0, act_);
    epi_hb<1>(acc, 0, wave, lg, lr, A.fb1, HBx, 136, true);
  }
  __syncthreads();
  { // out = s1 + bn(h @ f_w2 + b2) -> global fp32
    const u16* cb[2]={HBx,HBx}; const int cs[2]={136,136}; const int ck[2]={0,64};
    f32x4 acc[1];
    run_gemm3<2,8,1,1>(wave,lane,cb,cs,ck, A.wt+WT_F2, acc, ntile, mt0, act_);
    const int col = wave*16+lr;
    const float b2  = A.fb2[col];
    const float sc2 = A.fg[col] * rsqrtf(A.fv[col] + 1e-5f);
    const float sh2 = A.fbb[col] - A.fm[col]*sc2;
#pragma unroll
    for (int j=0;j<4;j++){
      int row = lg*4+j;
      float v = S1F[row*128+col] + (acc[0][j]+b2)*sc2 + sh2;
      A.outS[(size_t)(n0+row)*128 + col] = v;
    }
  }
}

// ---------------- launch ----------------
extern "C" void kernel_launch(void* const* d_in, const int* in_sizes, int n_in,
                              void* d_out, int out_size, void* d_ws, size_t ws_size,
                              hipStream_t stream)
{
  const float* sG = (const float*)d_in[0];
  const float* zG = (const float*)d_in[1];
  const int* eiG = (const int*)d_in[2];
  char* ws = (char*)d_ws;
  u16*  wt  = (u16*)ws;
  float* aw = (float*)(ws + AW_B);
  u16*  av  = (u16*)(ws + AV_B);
  int* cnt = (int*)(ws + CNT_B);
  int* cur = (int*)(ws + CUR_B);
  int* sta = (int*)(ws + STA_B);
  int* ord = (int*)(ws + ORD_B);
  float* outS = (float*)d_out;
  float* outZ = outS + (size_t)NN*128;

  hipMemsetAsync(cnt, 0, (size_t)NN*4, stream);

  PrepArgs P;
  const int srcIdx[11] = {29,31,3,5,7,9,11,13,15,21,23}; // e1,e2,w1,w2,w3,v1,v2,v3,o,f1,f2
  for (int i=0;i<11;i++) P.src[i] = (const float*)d_in[srcIdx[i]];
  P.dst = wt;
  setup_kernel<<<dim3(66 + (NE+255)/256), dim3(256), 0, stream>>>(P, eiG, cnt);
  scan_kernel<<<dim3(1), dim3(1024), 0, stream>>>(cnt, sta, cur);
  place_kernel<<<dim3((NE+255)/256), dim3(256), 0, stream>>>(eiG, cur, ord);

  EdgeArgs E;
  E.s = sG; E.z = zG; E.ei = eiG;
  E.wb1=(const float*)d_in[4];  E.wb2=(const float*)d_in[6];  E.wb3=(const float*)d_in[8];
  E.vb1=(const float*)d_in[10]; E.vb2=(const float*)d_in[12]; E.vb3=(const float*)d_in[14];
  E.eb1=(const float*)d_in[30]; E.eb2=(const float*)d_in[32];
  E.eg=(const float*)d_in[33]; E.ebb=(const float*)d_in[34]; E.em=(const float*)d_in[35]; E.ev=(const float*)d_in[36];
  E.wt = wt; E.aw = aw; E.av = av; E.zout = outZ;
  edge_kernel<<<dim3(NE/64), dim3(512), 0, stream>>>(E);

  NodeArgs Nd;
  Nd.s = sG; Nd.aw = aw; Nd.av = av; Nd.sta = sta; Nd.ord = ord; Nd.wt = wt;
  Nd.ob=(const float*)d_in[16]; Nd.og=(const float*)d_in[17]; Nd.obb=(const float*)d_in[18];
  Nd.om=(const float*)d_in[19]; Nd.ov=(const float*)d_in[20];
  Nd.fb1=(const float*)d_in[22]; Nd.fb2=(const float*)d_in[24];
  Nd.fg=(const float*)d_in[25]; Nd.fbb=(const float*)d_in[26]; Nd.fm=(const float*)d_in[27]; Nd.fv=(const float*)d_in[28];
  Nd.outS = outS;
  node_kernel<<<dim3(NN/16), dim3(512), 0, stream>>>(Nd);
}